// Round 9
// baseline (19123.596 us; speedup 1.0000x reference)
//
#include <hip/hip_runtime.h>
#include <math.h>

// Problem constants (match reference)
constexpr int B_   = 64;
constexpr int T_   = 200;
constexpr int L_IN = 100;
constexpr int S_   = 8;
constexpr int XC_  = 16;
constexpr int H_   = 256;
constexpr int W_   = 128;
constexpr int O_   = 8;
constexpr int GR_  = 3 * H_;      // 768
constexpr int HXC  = H_ * XC_;    // 4096

constexpr int NB   = 4;           // blocks per batch (team)
constexpr int ZPB  = 64;          // z-rows per block
constexpr int SLOT = 128;         // exchange payload slot (u64 elements)

#define NT 1024

// Workspace layout (floats)
constexpr size_t OFF_WIHT = 0;                               // [24][768]
constexpr size_t OFF_WHHT = OFF_WIHT + 24ull * GR_;          // [256][768]
constexpr size_t OFF_W2T  = OFF_WHHT + (size_t)H_ * GR_;     // [128][4096] k-major
constexpr size_t OFF_KX   = OFF_W2T + (size_t)W_ * HXC;      // [64][2][4][128] u64
constexpr size_t KX_U64   = (size_t)B_ * 2 * NB * SLOT;      // 65536 u64
constexpr size_t WS_FLOATS = OFF_KX + KX_U64 * 2;            // ~3.48 MB

// Transpose: in is R x K row-major; out[k*R + j] = in[j*K + k]
__global__ void transpose_kernel(const float* __restrict__ in, float* __restrict__ out,
                                 int R, int K) {
    int o = blockIdx.x * blockDim.x + threadIdx.x;
    if (o < R * K) {
        int k = o / R;
        int j = o - k * R;
        out[o] = in[j * K + k];
    }
}

__device__ __forceinline__ float softplus_f(float x) {
    return fmaxf(x, 0.f) + log1pf(expf(-fabsf(x)));
}
__device__ __forceinline__ float sigmoid_f(float x) {
    return 1.f / (1.f + expf(-x));
}

// ---------------------------------------------------------------------------
// R9: R8 skeleton (4-block teams, tagged-u64 single-RT exchange, LDS W2 tile)
// + W2 stream restructured as 3x8 float4 register BURSTS (max outstanding
// loads; latency hiding inside the phase — cross-phase prefetch is defeated
// by the vmcnt drain at every __syncthreads). No fake persistent W2 regs.
// ---------------------------------------------------------------------------
__global__ __launch_bounds__(NT, 4) void gru_cde_dist(
    const float* __restrict__ y_past,   // [B][L_IN][S]
    const float* __restrict__ tvals,    // [T]
    const float* __restrict__ cx,       // [B][T][XC-1]
    const float* __restrict__ wihT,     // [24][768]
    const float* __restrict__ whhT,     // [256][768]
    const float* __restrict__ gru_b,    // [768]
    const float* __restrict__ gru_bn,   // [256]
    const float* __restrict__ w0,       // [128][256] row-major
    const float* __restrict__ b0,       // [128]
    const float* __restrict__ w1,       // [128][128] row-major
    const float* __restrict__ b1,       // [128]
    const float* __restrict__ w2T,      // [128][4096] k-major
    const float* __restrict__ b2,       // [4096]
    const float* __restrict__ ro_w,     // [8][256]
    const float* __restrict__ ro_b,     // [8]
    unsigned long long* __restrict__ kx, // [64][2][4][128] tagged payload
    float* __restrict__ out)            // [B][100][8]
{
    const int b   = blockIdx.x & (B_ - 1);   // batch
    const int q   = blockIdx.x >> 6;         // quarter 0..3
    const int tid = threadIdx.x;

    __shared__ __align__(16) float z[H_];
    __shared__ __align__(16) float zsq[ZPB];
    __shared__ float kbq[5][ZPB];
    __shared__ __align__(16) float a0s[W_];
    __shared__ __align__(16) float a1s[W_];
    __shared__ float vown[W_];
    __shared__ float red[3][W_];
    __shared__ __align__(16) float4 red4[4][256];
    __shared__ float gsum[192];
    __shared__ float gaux[ZPB];
    __shared__ float xb[S_ + XC_];
    __shared__ float dxs[XC_];
    __shared__ __align__(16) float4 w2lds[4][8][256];   // 128 KB: planes 0..7/kgrp

    int  epoch = 0;
    bool dead  = false;
    float hh   = 0.f;

    auto slotbase = [&](int qq) -> size_t {
        return (((size_t)b * 2 + (epoch & 1)) * NB + qq) * SLOT;
    };
    auto publish_u64 = [&](int elem, float v) {
        unsigned long long pk = ((unsigned long long)(unsigned)epoch << 32)
                              | (unsigned long long)__float_as_uint(v);
        __hip_atomic_store(&kx[slotbase(q) + elem], pk,
                           __ATOMIC_RELAXED, __HIP_MEMORY_SCOPE_AGENT);
    };
    auto poll_u64 = [&](int qq, int elem) -> float {
        unsigned long long pk = 0;
        int guard = 0;
        for (;;) {
            pk = __hip_atomic_load(&kx[slotbase(qq) + elem],
                                   __ATOMIC_RELAXED, __HIP_MEMORY_SCOPE_AGENT);
            if ((unsigned)(pk >> 32) >= (unsigned)epoch) break;
            if (++guard > (1 << 20)) { dead = true; break; }
        }
        return __uint_as_float((unsigned)pk);
    };

    // ---------------- Encoder: 100 GRU steps, 2 syncs/step -------------------
    const int   seg = tid >> 6;          // 0=reset,1=update,2=new (tid<192)
    const int   l63 = tid & 63;
    const int   grow = seg * H_ + q * ZPB + l63;
    const float gbr = (tid < 192) ? gru_b[grow] : 0.f;
    const float bnr = (tid < ZPB) ? gru_bn[q * ZPB + tid] : 0.f;

    if (tid < H_) z[tid] = 0.f;
    if (tid < S_ + XC_) {    // xb for step 0
        float v;
        if (tid < S_)                v = y_past[(b * L_IN) * S_ + tid];
        else if (tid < S_ + XC_ - 1) v = cx[(b * T_) * (XC_ - 1) + (tid - S_)];
        else                         v = tvals[0];
        xb[tid] = v;
    }
    __syncthreads();

    for (int step = 0; step < L_IN; ++step) {
        if (tid < 192) {    // phase A: gate pre-activations
            float ig = gbr;
            #pragma unroll
            for (int k = 0; k < S_ + XC_; ++k) ig += wihT[k * GR_ + grow] * xb[k];
            float hg = 0.f, hg2 = 0.f;
            #pragma unroll 8
            for (int k = 0; k < H_; k += 2) {
                hg  += whhT[k * GR_ + grow]       * z[k];
                hg2 += whhT[(k + 1) * GR_ + grow] * z[k + 1];
            }
            hg += hg2;
            if (seg < 2) gsum[tid] = ig + hg;
            else { gsum[tid] = ig; gaux[l63] = hg; }
        }
        __syncthreads();
        epoch++;
        // phase B: update+publish / gather / preload xb
        if (tid < ZPB) {
            float rr = sigmoid_f(gsum[tid]);
            float uu = sigmoid_f(gsum[64 + tid]);
            float nn = tanhf(gsum[128 + tid] + rr * (gaux[tid] + bnr));
            float zo = z[q * ZPB + tid];
            float znew = nn + uu * (zo - nn);
            z[q * ZPB + tid] = znew;
            publish_u64(tid, znew);
        } else if (tid < 256) {
            if (!dead) {
                int pp = tid >> 6;               // 1..3
                int qq = (q + pp) & 3;
                int e  = tid & 63;
                float v = poll_u64(qq, e);
                z[qq * 64 + e] = v;
            }
        } else if (tid < 256 + S_ + XC_ && step + 1 < L_IN) {
            int c = tid - 256;
            float v;
            if (c < S_)                v = y_past[(b * L_IN + step + 1) * S_ + c];
            else if (c < S_ + XC_ - 1) v = cx[(b * T_ + step + 1) * (XC_ - 1) + (c - S_)];
            else                       v = tvals[step + 1];
            xb[c] = v;
        }
        __syncthreads();
    }

    // readout (block q==0 only; its z is full after encoder gathers)
    auto readout = [&](int idx) {
        if (q == 0 && tid < 8 * 64) {
            int o  = tid >> 6;
            int kk = tid & 63;
            float4 wv = reinterpret_cast<const float4*>(ro_w)[o * 64 + kk];
            float4 zv = *reinterpret_cast<const float4*>(&z[kk * 4]);
            float p = wv.x * zv.x + wv.y * zv.y + wv.z * zv.z + wv.w * zv.w;
            p += __shfl_xor(p, 1);
            p += __shfl_xor(p, 2);
            p += __shfl_xor(p, 4);
            p += __shfl_xor(p, 8);
            p += __shfl_xor(p, 16);
            p += __shfl_xor(p, 32);
            if (kk == 0) out[(b * L_IN + idx) * O_ + o] = p + ro_b[o];
        }
    };

    readout(0);

    // ---------------- ODE weight residency ----------------------------------
    const int wv_ = tid >> 6;            // wave 0..15
    const int ln  = tid & 63;            // lane
    const int vr  = wv_ * 8 + (ln >> 3); // matvec row 0..127
    const int vc  = ln & 7;              // k-chunk 0..7
    const int g2  = tid >> 8;            // W2 k-group 0..3
    const int u   = tid & 255;           // W2 row-quad 0..255

    const float4* __restrict__ w04  = reinterpret_cast<const float4*>(w0);
    const float4* __restrict__ w14  = reinterpret_cast<const float4*>(w1);
    const float4* __restrict__ w2T4 = reinterpret_cast<const float4*>(w2T);

    // W0 row vr, cols q*64 + vc*8 .. +7  (8 floats)
    const float4 w0r0 = w04[vr * 64 + q * 16 + vc * 2];
    const float4 w0r1 = w04[vr * 64 + q * 16 + vc * 2 + 1];
    // W1 row vr, cols vc*16 .. +15  (16 floats)
    const float4 w1r0 = w14[vr * 32 + vc * 4 + 0];
    const float4 w1r1 = w14[vr * 32 + vc * 4 + 1];
    const float4 w1r2 = w14[vr * 32 + vc * 4 + 2];
    const float4 w1r3 = w14[vr * 32 + vc * 4 + 3];
    // W2 LDS planes 0..7 of each k-group (32 planes, 128 KB), loaded once
    for (int it = 0; it < 8; ++it) {
        int L   = it * 1024 + tid;
        int g2l = L >> 11;
        int jl  = (L >> 8) & 7;
        int ul  = L & 255;
        w2lds[g2l][jl][ul] =
            w2T4[(size_t)(g2l * 32 + jl) * 1024 + (size_t)q * 256 + ul];
    }

    const float b0r = (tid < W_) ? b0[tid] : 0.f;
    const float b1r = b1[vr];
    float4 b2c = make_float4(0.f, 0.f, 0.f, 0.f);
    if (tid < 256) b2c = reinterpret_cast<const float4*>(b2)[q * 256 + tid];
    float4 dx4 = make_float4(0.f, 0.f, 0.f, 0.f);
    __syncthreads();   // w2lds ready

    // ---------------- ODE: 99 intervals x 2 dopri5 substeps ------------------
    for (int i = 0; i < T_ - L_IN - 1; ++i) {
        float dt = tvals[L_IN + i + 1] - tvals[L_IN + i];
        hh = dt * 0.5f;   // N_SUB = 2
        if (tid < XC_) {
            float xa, xbv;
            if (tid < XC_ - 1) {
                xa  = cx[(b * T_ + L_IN + i) * (XC_ - 1) + tid];
                xbv = cx[(b * T_ + L_IN + i + 1) * (XC_ - 1) + tid];
            } else {
                xa  = tvals[L_IN + i];
                xbv = tvals[L_IN + i + 1];
            }
            dxs[tid] = (xbv - xa) / dt;
        }
        __syncthreads();
        if (tid < 256) {
            int c0 = (tid & 3) * 4;
            dx4 = make_float4(dxs[c0], dxs[c0 + 1], dxs[c0 + 2], dxs[c0 + 3]);
        }

        for (int sub = 0; sub < 2; ++sub) {
            if (tid < ZPB) zsq[tid] = z[q * ZPB + tid];
            __syncthreads();

            for (int s = 0; s < 6; ++s) {
                epoch++;
                // ---- V: v-partial = W0own @ zsq, wave-shuffle reduce --------
                {
                    const float* zp = &zsq[vc * 8];
                    float pv = w0r0.x * zp[0] + w0r0.y * zp[1]
                             + w0r0.z * zp[2] + w0r0.w * zp[3]
                             + w0r1.x * zp[4] + w0r1.y * zp[5]
                             + w0r1.z * zp[6] + w0r1.w * zp[7];
                    pv += __shfl_xor(pv, 1);
                    pv += __shfl_xor(pv, 2);
                    pv += __shfl_xor(pv, 4);
                    if ((ln & 7) == 0) {
                        vown[vr] = pv;
                        publish_u64(vr, pv);
                    }
                }
                __syncthreads();   // 1
                // ---- GATHER: 384 threads, one tagged u64 each ---------------
                if (tid < 384 && !dead) {
                    int pp = tid >> 7;
                    int e  = tid & 127;
                    int qq = pp + (pp >= q);
                    red[pp][e] = poll_u64(qq, e);
                }
                __syncthreads();   // 2
                // ---- A0 ----------------------------------------------------
                if (tid < W_) {
                    float gv = vown[tid] + red[0][tid] + red[1][tid]
                             + red[2][tid] + b0r;
                    a0s[tid] = softplus_f(gv);
                }
                __syncthreads();   // 3
                // ---- A1: W1 @ a0, wave-shuffle reduce -----------------------
                {
                    const float4* ap = reinterpret_cast<const float4*>(a0s) + vc * 4;
                    float4 a0v = ap[0], a1v = ap[1], a2v = ap[2], a3v = ap[3];
                    float pa = w1r0.x * a0v.x + w1r0.y * a0v.y
                             + w1r0.z * a0v.z + w1r0.w * a0v.w
                             + w1r1.x * a1v.x + w1r1.y * a1v.y
                             + w1r1.z * a1v.z + w1r1.w * a1v.w
                             + w1r2.x * a2v.x + w1r2.y * a2v.y
                             + w1r2.z * a2v.z + w1r2.w * a2v.w
                             + w1r3.x * a3v.x + w1r3.y * a3v.y
                             + w1r3.z * a3v.z + w1r3.w * a3v.w;
                    pa += __shfl_xor(pa, 1);
                    pa += __shfl_xor(pa, 2);
                    pa += __shfl_xor(pa, 4);
                    if ((ln & 7) == 0) a1s[vr] = softplus_f(pa + b1r);
                }
                __syncthreads();   // 4
                // ---- W2: 8 LDS planes + 24 streamed in 3x8 register bursts --
                {
                    const int base = g2 * 32;
                    const float4* wp = w2T4 + (size_t)(base + 8) * 1024
                                     + (size_t)q * 256 + u;
                    // burst 1: planes 8..15 (issue all 8 loads back-to-back)
                    float4 s0 = wp[0 * 1024], s1 = wp[1 * 1024];
                    float4 s2 = wp[2 * 1024], s3 = wp[3 * 1024];
                    float4 s4 = wp[4 * 1024], s5 = wp[5 * 1024];
                    float4 s6 = wp[6 * 1024], s7 = wp[7 * 1024];
                    float4 acc = make_float4(0.f, 0.f, 0.f, 0.f);
                    // MAC LDS planes 0..7 while burst 1 is in flight
                    #pragma unroll
                    for (int jl = 0; jl < 8; ++jl) {
                        float4 wvv = w2lds[g2][jl][u];
                        float av = a1s[base + jl];
                        acc.x += wvv.x * av; acc.y += wvv.y * av;
                        acc.z += wvv.z * av; acc.w += wvv.w * av;
                    }
                    #define MACS(v_, idx_) { float av_ = a1s[base + (idx_)]; \
                        acc.x += (v_).x * av_; acc.y += (v_).y * av_; \
                        acc.z += (v_).z * av_; acc.w += (v_).w * av_; }
                    // burst 2: planes 16..23
                    float4 t0 = wp[8 * 1024],  t1 = wp[9 * 1024];
                    float4 t2 = wp[10 * 1024], t3 = wp[11 * 1024];
                    float4 t4 = wp[12 * 1024], t5 = wp[13 * 1024];
                    float4 t6 = wp[14 * 1024], t7 = wp[15 * 1024];
                    // MAC burst 1 while burst 2 is in flight
                    MACS(s0, 8)  MACS(s1, 9)  MACS(s2, 10) MACS(s3, 11)
                    MACS(s4, 12) MACS(s5, 13) MACS(s6, 14) MACS(s7, 15)
                    // burst 3: planes 24..31
                    float4 u0 = wp[16 * 1024], u1 = wp[17 * 1024];
                    float4 u2 = wp[18 * 1024], u3 = wp[19 * 1024];
                    float4 u4 = wp[20 * 1024], u5 = wp[21 * 1024];
                    float4 u6 = wp[22 * 1024], u7 = wp[23 * 1024];
                    // MAC burst 2 while burst 3 is in flight, then burst 3
                    MACS(t0, 16) MACS(t1, 17) MACS(t2, 18) MACS(t3, 19)
                    MACS(t4, 20) MACS(t5, 21) MACS(t6, 22) MACS(t7, 23)
                    MACS(u0, 24) MACS(u1, 25) MACS(u2, 26) MACS(u3, 27)
                    MACS(u4, 28) MACS(u5, 29) MACS(u6, 30) MACS(u7, 31)
                    #undef MACS
                    red4[g2][u] = acc;
                }
                __syncthreads();   // 5
                // ---- COMBINE: k-reduce, tanh, dx-dot, state update ----------
                if (tid < 256) {
                    float4 t0 = red4[0][tid], t1 = red4[1][tid];
                    float4 t2 = red4[2][tid], t3 = red4[3][tid];
                    float p = tanhf(t0.x + t1.x + t2.x + t3.x + b2c.x) * dx4.x
                            + tanhf(t0.y + t1.y + t2.y + t3.y + b2c.y) * dx4.y
                            + tanhf(t0.z + t1.z + t2.z + t3.z + b2c.z) * dx4.z
                            + tanhf(t0.w + t1.w + t2.w + t3.w + b2c.w) * dx4.w;
                    p += __shfl_xor(p, 1);
                    p += __shfl_xor(p, 2);
                    if ((tid & 3) == 0) {
                        int ii = tid >> 2;
                        float kv = p;
                        float zc = z[q * ZPB + ii];
                        if (s == 0) {
                            kbq[0][ii] = kv;
                            zsq[ii] = zc + hh * (0.2f * kv);
                        } else if (s == 1) {
                            kbq[1][ii] = kv;
                            zsq[ii] = zc + hh * (0.075f * kbq[0][ii] + 0.225f * kv);
                        } else if (s == 2) {
                            kbq[2][ii] = kv;
                            zsq[ii] = zc + hh * ((44.f / 45.f) * kbq[0][ii]
                                               - (56.f / 15.f) * kbq[1][ii]
                                               + (32.f / 9.f) * kv);
                        } else if (s == 3) {
                            kbq[3][ii] = kv;
                            zsq[ii] = zc + hh * ((19372.f / 6561.f) * kbq[0][ii]
                                               - (25360.f / 2187.f) * kbq[1][ii]
                                               + (64448.f / 6561.f) * kbq[2][ii]
                                               - (212.f / 729.f) * kv);
                        } else if (s == 4) {
                            kbq[4][ii] = kv;
                            zsq[ii] = zc + hh * ((9017.f / 3168.f) * kbq[0][ii]
                                               - (355.f / 33.f) * kbq[1][ii]
                                               + (46732.f / 5247.f) * kbq[2][ii]
                                               + (49.f / 176.f) * kbq[3][ii]
                                               - (5103.f / 18656.f) * kv);
                        } else {
                            z[q * ZPB + ii] = zc + hh * ((35.f / 384.f) * kbq[0][ii]
                                                       + (500.f / 1113.f) * kbq[2][ii]
                                                       + (125.f / 192.f) * kbq[3][ii]
                                                       - (2187.f / 6784.f) * kbq[4][ii]
                                                       + (11.f / 84.f) * kv);
                        }
                    }
                }
                __syncthreads();   // 6
            }   // stages
        }       // substeps

        // ---- z to block 0 for readout (one-way) ----
        epoch++;
        if (tid < ZPB) publish_u64(tid, z[q * ZPB + tid]);
        if (q == 0 && tid >= 64 && tid < 256 && !dead) {
            int pp = tid >> 6;       // 1..3
            int e  = tid & 63;
            z[pp * 64 + e] = poll_u64(pp, e);
        }
        __syncthreads();
        readout(i + 1);
    }
}

// ---------------------------------------------------------------------------
// Fallback (ws too small): monolithic kernel, original weight layouts.
// ---------------------------------------------------------------------------
__global__ __launch_bounds__(NT) void gru_cde_mono(
    const float* __restrict__ y_past, const float* __restrict__ tvals,
    const float* __restrict__ cx,
    const float* __restrict__ wih, const float* __restrict__ whh,
    const float* __restrict__ gru_b, const float* __restrict__ gru_bn,
    const float* __restrict__ w0, const float* __restrict__ b0,
    const float* __restrict__ w1, const float* __restrict__ b1,
    const float* __restrict__ w2, const float* __restrict__ b2,
    const float* __restrict__ ro_w, const float* __restrict__ ro_b,
    float* __restrict__ out)
{
    const int b   = blockIdx.x;
    const int tid = threadIdx.x;

    __shared__ __align__(16) float z[H_];
    __shared__ float zsv[H_];
    __shared__ float kbv[6][H_];
    __shared__ float a0v[W_];
    __shared__ float a1v[W_];
    __shared__ float redv[8][W_];
    __shared__ float gsum[GR_];
    __shared__ float gaux[H_];
    __shared__ float xb[S_ + XC_];
    __shared__ float dxsv[XC_];

    const float gb_t = (tid < GR_) ? gru_b[tid] : 0.f;
    const float bn_t = (tid < H_) ? gru_bn[tid] : 0.f;
    const float4 bb = reinterpret_cast<const float4*>(b2)[tid];

    if (tid < H_) z[tid] = 0.f;
    __syncthreads();

    for (int step = 0; step < L_IN; ++step) {
        if (tid < S_ + XC_) {
            float v;
            if (tid < S_)                v = y_past[(b * L_IN + step) * S_ + tid];
            else if (tid < S_ + XC_ - 1) v = cx[(b * T_ + step) * (XC_ - 1) + (tid - S_)];
            else                         v = tvals[step];
            xb[tid] = v;
        }
        __syncthreads();
        if (tid < GR_) {
            float ig = gb_t;
            #pragma unroll
            for (int k = 0; k < S_ + XC_; ++k) ig += wih[tid * (S_ + XC_) + k] * xb[k];
            float hg = 0.f;
            #pragma unroll 8
            for (int k = 0; k < H_; ++k) hg += whh[tid * H_ + k] * z[k];
            if (tid < 2 * H_) gsum[tid] = ig + hg;
            else { gsum[tid] = ig; gaux[tid - 2 * H_] = hg; }
        }
        __syncthreads();
        if (tid < H_) {
            float r = sigmoid_f(gsum[tid]);
            float u = sigmoid_f(gsum[tid + H_]);
            float n = tanhf(gsum[tid + 2 * H_] + r * (gaux[tid] + bn_t));
            z[tid] = n + u * (z[tid] - n);
        }
        __syncthreads();
    }

    auto readout = [&](int idx) {
        if (tid < 8 * 64) {
            int o  = tid >> 6;
            int kk = tid & 63;
            float4 wv = reinterpret_cast<const float4*>(ro_w)[o * 64 + kk];
            float4 zv = *reinterpret_cast<const float4*>(&z[kk * 4]);
            float p = wv.x * zv.x + wv.y * zv.y + wv.z * zv.z + wv.w * zv.w;
            p += __shfl_xor(p, 1);
            p += __shfl_xor(p, 2);
            p += __shfl_xor(p, 4);
            p += __shfl_xor(p, 8);
            p += __shfl_xor(p, 16);
            p += __shfl_xor(p, 32);
            if (kk == 0) out[(b * L_IN + idx) * O_ + o] = p + ro_b[o];
        }
    };

    readout(0);

    auto vf = [&](const float* zin, int s) {
        const int g = tid >> 7;
        const int r = tid & 127;
        {
            float acc = 0.f;
            const int k0 = g * 32;
            #pragma unroll 8
            for (int k = k0; k < k0 + 32; ++k) acc += w0[r * H_ + k] * zin[k];
            redv[g][r] = acc;
        }
        __syncthreads();
        if (tid < W_) {
            float sa = b0[tid];
            #pragma unroll
            for (int gg = 0; gg < 8; ++gg) sa += redv[gg][tid];
            a0v[tid] = softplus_f(sa);
        }
        __syncthreads();
        {
            float acc = 0.f;
            const int k0 = g * 16;
            #pragma unroll
            for (int k = k0; k < k0 + 16; ++k) acc += w1[r * W_ + k] * a0v[k];
            redv[g][r] = acc;
        }
        __syncthreads();
        if (tid < W_) {
            float sa = b1[tid];
            #pragma unroll
            for (int gg = 0; gg < 8; ++gg) sa += redv[gg][tid];
            a1v[tid] = softplus_f(sa);
        }
        __syncthreads();
        {
            float4 acc = make_float4(0.f, 0.f, 0.f, 0.f);
            const int jj = tid * 4;
            #pragma unroll 4
            for (int k = 0; k < W_; ++k) {
                float av = a1v[k];
                acc.x += w2[(jj + 0) * W_ + k] * av;
                acc.y += w2[(jj + 1) * W_ + k] * av;
                acc.z += w2[(jj + 2) * W_ + k] * av;
                acc.w += w2[(jj + 3) * W_ + k] * av;
            }
            const int c0 = jj & 15;
            float p = tanhf(acc.x + bb.x) * dxsv[c0]
                    + tanhf(acc.y + bb.y) * dxsv[c0 + 1]
                    + tanhf(acc.z + bb.z) * dxsv[c0 + 2]
                    + tanhf(acc.w + bb.w) * dxsv[c0 + 3];
            p += __shfl_xor(p, 1);
            p += __shfl_xor(p, 2);
            if ((tid & 3) == 0) kbv[s][tid >> 2] = p;
        }
        __syncthreads();
    };

    for (int i = 0; i < T_ - L_IN - 1; ++i) {
        float dt = tvals[L_IN + i + 1] - tvals[L_IN + i];
        if (tid < XC_) {
            float xa, xbv;
            if (tid < XC_ - 1) {
                xa  = cx[(b * T_ + L_IN + i) * (XC_ - 1) + tid];
                xbv = cx[(b * T_ + L_IN + i + 1) * (XC_ - 1) + tid];
            } else {
                xa  = tvals[L_IN + i];
                xbv = tvals[L_IN + i + 1];
            }
            dxsv[tid] = (xbv - xa) / dt;
        }
        const float hh = dt * 0.5f;
        __syncthreads();

        for (int sub = 0; sub < 2; ++sub) {
            vf(z, 0);
            if (tid < H_) zsv[tid] = z[tid] + hh * (0.2f * kbv[0][tid]);
            __syncthreads();
            vf(zsv, 1);
            if (tid < H_) zsv[tid] = z[tid] + hh * (0.075f * kbv[0][tid] + 0.225f * kbv[1][tid]);
            __syncthreads();
            vf(zsv, 2);
            if (tid < H_) zsv[tid] = z[tid] + hh * ((44.f / 45.f) * kbv[0][tid]
                                                - (56.f / 15.f) * kbv[1][tid]
                                                + (32.f / 9.f) * kbv[2][tid]);
            __syncthreads();
            vf(zsv, 3);
            if (tid < H_) zsv[tid] = z[tid] + hh * ((19372.f / 6561.f) * kbv[0][tid]
                                                - (25360.f / 2187.f) * kbv[1][tid]
                                                + (64448.f / 6561.f) * kbv[2][tid]
                                                - (212.f / 729.f) * kbv[3][tid]);
            __syncthreads();
            vf(zsv, 4);
            if (tid < H_) zsv[tid] = z[tid] + hh * ((9017.f / 3168.f) * kbv[0][tid]
                                                - (355.f / 33.f) * kbv[1][tid]
                                                + (46732.f / 5247.f) * kbv[2][tid]
                                                + (49.f / 176.f) * kbv[3][tid]
                                                - (5103.f / 18656.f) * kbv[4][tid]);
            __syncthreads();
            vf(zsv, 5);
            if (tid < H_) {
                z[tid] = z[tid] + hh * ((35.f / 384.f) * kbv[0][tid]
                                      + (500.f / 1113.f) * kbv[2][tid]
                                      + (125.f / 192.f) * kbv[3][tid]
                                      - (2187.f / 6784.f) * kbv[4][tid]
                                      + (11.f / 84.f) * kbv[5][tid]);
            }
            __syncthreads();
        }
        readout(i + 1);
    }
}

extern "C" void kernel_launch(void* const* d_in, const int* in_sizes, int n_in,
                              void* d_out, int out_size, void* d_ws, size_t ws_size,
                              hipStream_t stream) {
    const float* y_past = (const float*)d_in[0];
    const float* tvals  = (const float*)d_in[1];
    const float* cx     = (const float*)d_in[2];
    const float* wih    = (const float*)d_in[3];
    const float* whh    = (const float*)d_in[4];
    const float* gb     = (const float*)d_in[5];
    const float* gbn    = (const float*)d_in[6];
    const float* w0     = (const float*)d_in[7];
    const float* b0     = (const float*)d_in[8];
    const float* w1     = (const float*)d_in[9];
    const float* b1     = (const float*)d_in[10];
    const float* w2     = (const float*)d_in[11];
    const float* b2     = (const float*)d_in[12];
    const float* ro_w   = (const float*)d_in[13];
    const float* ro_b   = (const float*)d_in[14];
    float* out = (float*)d_out;

    if (ws_size >= WS_FLOATS * sizeof(float)) {
        float* ws = (float*)d_ws;
        auto launchT = [&](const float* in, float* o, int R, int K) {
            int n = R * K;
            transpose_kernel<<<(n + 255) / 256, 256, 0, stream>>>(in, o, R, K);
        };
        launchT(wih, ws + OFF_WIHT, GR_, S_ + XC_);
        launchT(whh, ws + OFF_WHHT, GR_, H_);
        launchT(w2,  ws + OFF_W2T,  HXC, W_);
        // zero the tagged-exchange buffer (tags must start below epoch 1)
        hipMemsetAsync((char*)d_ws + OFF_KX * sizeof(float), 0,
                       KX_U64 * sizeof(unsigned long long), stream);
        gru_cde_dist<<<B_ * NB, NT, 0, stream>>>(
            y_past, tvals, cx,
            ws + OFF_WIHT, ws + OFF_WHHT, gb, gbn,
            w0, b0, w1, b1, ws + OFF_W2T, b2,
            ro_w, ro_b,
            (unsigned long long*)(ws + OFF_KX), out);
    } else {
        gru_cde_mono<<<B_, NT, 0, stream>>>(
            y_past, tvals, cx,
            wih, whh, gb, gbn,
            w0, b0, w1, b1, w2, b2,
            ro_w, ro_b, out);
    }
}

// Round 11
// 9610.906 us; speedup vs baseline: 1.9898x; 1.9898x over previous
//
#include <hip/hip_runtime.h>
#include <math.h>

// Problem constants (match reference)
constexpr int B_   = 64;
constexpr int T_   = 200;
constexpr int L_IN = 100;
constexpr int S_   = 8;
constexpr int XC_  = 16;
constexpr int H_   = 256;
constexpr int W_   = 128;
constexpr int O_   = 8;
constexpr int GR_  = 3 * H_;      // 768
constexpr int HXC  = H_ * XC_;    // 4096

constexpr int NB   = 4;           // blocks per batch (team)
constexpr int ZPB  = 64;          // z-rows per block
constexpr int SLOT = 128;         // exchange payload slot (u64 elements)

#define NT 1024

// Workspace layout (floats)
constexpr size_t OFF_WIHT = 0;                               // [24][768]
constexpr size_t OFF_WHHT = OFF_WIHT + 24ull * GR_;          // [256][768]
constexpr size_t OFF_W2T  = OFF_WHHT + (size_t)H_ * GR_;     // [128][4096] k-major
constexpr size_t OFF_KX   = OFF_W2T + (size_t)W_ * HXC;      // [64][2][4][128] u64
constexpr size_t KX_U64   = (size_t)B_ * 2 * NB * SLOT;      // 65536 u64
constexpr size_t WS_FLOATS = OFF_KX + KX_U64 * 2;            // ~3.48 MB

// Transpose: in is R x K row-major; out[k*R + j] = in[j*K + k]
__global__ void transpose_kernel(const float* __restrict__ in, float* __restrict__ out,
                                 int R, int K) {
    int o = blockIdx.x * blockDim.x + threadIdx.x;
    if (o < R * K) {
        int k = o / R;
        int j = o - k * R;
        out[o] = in[j * K + k];
    }
}

__device__ __forceinline__ float softplus_f(float x) {
    return fmaxf(x, 0.f) + log1pf(expf(-fabsf(x)));
}
__device__ __forceinline__ float sigmoid_f(float x) {
    return 1.f / (1.f + expf(-x));
}

// ---------------------------------------------------------------------------
// R11 = R10 resubmitted (R10 bench never ran: GPU acquisition timeout).
// R10 = R8 (proven 9.63 ms) + amdgpu_waves_per_eu(4,4).
// Diagnosis: __launch_bounds__(NT,4) sets waves-per-eu range [4,inf) and the
// allocator targets the range MAX (8/EU -> 64 VGPRs), silently demoting all
// "register-resident" weights to per-stage L2 reloads (R4..R9 all ran at 64
// VGPRs; R9's 24-deep bursts spilled to scratch -> L2 thrash -> 40 GB HBM).
// LDS 154 KB forces 1 block/CU = exactly 4 waves/EU, so pinning (4,4) frees
// the full 128-VGPR budget with zero occupancy loss.
// ---------------------------------------------------------------------------
__global__ __attribute__((amdgpu_waves_per_eu(4, 4)))
__launch_bounds__(NT) void gru_cde_dist(
    const float* __restrict__ y_past,   // [B][L_IN][S]
    const float* __restrict__ tvals,    // [T]
    const float* __restrict__ cx,       // [B][T][XC-1]
    const float* __restrict__ wihT,     // [24][768]
    const float* __restrict__ whhT,     // [256][768]
    const float* __restrict__ gru_b,    // [768]
    const float* __restrict__ gru_bn,   // [256]
    const float* __restrict__ w0,       // [128][256] row-major
    const float* __restrict__ b0,       // [128]
    const float* __restrict__ w1,       // [128][128] row-major
    const float* __restrict__ b1,       // [128]
    const float* __restrict__ w2T,      // [128][4096] k-major
    const float* __restrict__ b2,       // [4096]
    const float* __restrict__ ro_w,     // [8][256]
    const float* __restrict__ ro_b,     // [8]
    unsigned long long* __restrict__ kx, // [64][2][4][128] tagged payload
    float* __restrict__ out)            // [B][100][8]
{
    const int b   = blockIdx.x & (B_ - 1);   // batch
    const int q   = blockIdx.x >> 6;         // quarter 0..3
    const int tid = threadIdx.x;

    __shared__ __align__(16) float z[H_];
    __shared__ __align__(16) float zsq[ZPB];
    __shared__ float kbq[5][ZPB];
    __shared__ __align__(16) float a0s[W_];
    __shared__ __align__(16) float a1s[W_];
    __shared__ float vown[W_];
    __shared__ float red[3][W_];
    __shared__ __align__(16) float4 red4[4][256];
    __shared__ float gsum[192];
    __shared__ float gaux[ZPB];
    __shared__ float xb[S_ + XC_];
    __shared__ float dxs[XC_];
    __shared__ __align__(16) float4 w2lds[4][8][256];   // 128 KB: 32 W2 k-planes

    int  epoch = 0;
    bool dead  = false;
    float hh   = 0.f;

    auto slotbase = [&](int qq) -> size_t {
        return (((size_t)b * 2 + (epoch & 1)) * NB + qq) * SLOT;
    };
    auto publish_u64 = [&](int elem, float v) {
        unsigned long long pk = ((unsigned long long)(unsigned)epoch << 32)
                              | (unsigned long long)__float_as_uint(v);
        __hip_atomic_store(&kx[slotbase(q) + elem], pk,
                           __ATOMIC_RELAXED, __HIP_MEMORY_SCOPE_AGENT);
    };
    auto poll_u64 = [&](int qq, int elem) -> float {
        unsigned long long pk = 0;
        int guard = 0;
        for (;;) {
            pk = __hip_atomic_load(&kx[slotbase(qq) + elem],
                                   __ATOMIC_RELAXED, __HIP_MEMORY_SCOPE_AGENT);
            if ((unsigned)(pk >> 32) >= (unsigned)epoch) break;
            if (++guard > (1 << 20)) { dead = true; break; }
        }
        return __uint_as_float((unsigned)pk);
    };

    // ---------------- Encoder: 100 GRU steps, 2 syncs/step -------------------
    const int   seg = tid >> 6;          // 0=reset,1=update,2=new (tid<192)
    const int   l63 = tid & 63;
    const int   grow = seg * H_ + q * ZPB + l63;
    const float gbr = (tid < 192) ? gru_b[grow] : 0.f;
    const float bnr = (tid < ZPB) ? gru_bn[q * ZPB + tid] : 0.f;

    if (tid < H_) z[tid] = 0.f;
    if (tid < S_ + XC_) {    // xb for step 0
        float v;
        if (tid < S_)                v = y_past[(b * L_IN) * S_ + tid];
        else if (tid < S_ + XC_ - 1) v = cx[(b * T_) * (XC_ - 1) + (tid - S_)];
        else                         v = tvals[0];
        xb[tid] = v;
    }
    __syncthreads();

    for (int step = 0; step < L_IN; ++step) {
        if (tid < 192) {    // phase A: gate pre-activations
            float ig = gbr;
            #pragma unroll
            for (int k = 0; k < S_ + XC_; ++k) ig += wihT[k * GR_ + grow] * xb[k];
            float hg = 0.f, hg2 = 0.f;
            #pragma unroll 8
            for (int k = 0; k < H_; k += 2) {
                hg  += whhT[k * GR_ + grow]       * z[k];
                hg2 += whhT[(k + 1) * GR_ + grow] * z[k + 1];
            }
            hg += hg2;
            if (seg < 2) gsum[tid] = ig + hg;
            else { gsum[tid] = ig; gaux[l63] = hg; }
        }
        __syncthreads();
        epoch++;
        // phase B: update+publish / gather / preload xb
        if (tid < ZPB) {
            float rr = sigmoid_f(gsum[tid]);
            float uu = sigmoid_f(gsum[64 + tid]);
            float nn = tanhf(gsum[128 + tid] + rr * (gaux[tid] + bnr));
            float zo = z[q * ZPB + tid];
            float znew = nn + uu * (zo - nn);
            z[q * ZPB + tid] = znew;
            publish_u64(tid, znew);
        } else if (tid < 256) {
            if (!dead) {
                int pp = tid >> 6;               // 1..3
                int qq = (q + pp) & 3;
                int e  = tid & 63;
                float v = poll_u64(qq, e);
                z[qq * 64 + e] = v;
            }
        } else if (tid < 256 + S_ + XC_ && step + 1 < L_IN) {
            int c = tid - 256;
            float v;
            if (c < S_)                v = y_past[(b * L_IN + step + 1) * S_ + c];
            else if (c < S_ + XC_ - 1) v = cx[(b * T_ + step + 1) * (XC_ - 1) + (c - S_)];
            else                       v = tvals[step + 1];
            xb[c] = v;
        }
        __syncthreads();
    }

    // readout (block q==0 only; its z is full after encoder gathers)
    auto readout = [&](int idx) {
        if (q == 0 && tid < 8 * 64) {
            int o  = tid >> 6;
            int kk = tid & 63;
            float4 wv = reinterpret_cast<const float4*>(ro_w)[o * 64 + kk];
            float4 zv = *reinterpret_cast<const float4*>(&z[kk * 4]);
            float p = wv.x * zv.x + wv.y * zv.y + wv.z * zv.z + wv.w * zv.w;
            p += __shfl_xor(p, 1);
            p += __shfl_xor(p, 2);
            p += __shfl_xor(p, 4);
            p += __shfl_xor(p, 8);
            p += __shfl_xor(p, 16);
            p += __shfl_xor(p, 32);
            if (kk == 0) out[(b * L_IN + idx) * O_ + o] = p + ro_b[o];
        }
    };

    readout(0);

    // ---------------- ODE weight residency (128-VGPR budget) -----------------
    const int wv_ = tid >> 6;            // wave 0..15
    const int ln  = tid & 63;            // lane
    const int vr  = wv_ * 8 + (ln >> 3); // matvec row 0..127
    const int vc  = ln & 7;              // k-chunk 0..7
    const int g2  = tid >> 8;            // W2 k-group 0..3
    const int u   = tid & 255;           // W2 row-quad 0..255

    const float4* __restrict__ w04  = reinterpret_cast<const float4*>(w0);
    const float4* __restrict__ w14  = reinterpret_cast<const float4*>(w1);
    const float4* __restrict__ w2T4 = reinterpret_cast<const float4*>(w2T);

    // W0 row vr, cols q*64 + vc*8 .. +7  (8 floats)
    const float4 w0r0 = w04[vr * 64 + q * 16 + vc * 2];
    const float4 w0r1 = w04[vr * 64 + q * 16 + vc * 2 + 1];
    // W1 row vr, cols vc*16 .. +15  (16 floats)
    const float4 w1r0 = w14[vr * 32 + vc * 4 + 0];
    const float4 w1r1 = w14[vr * 32 + vc * 4 + 1];
    const float4 w1r2 = w14[vr * 32 + vc * 4 + 2];
    const float4 w1r3 = w14[vr * 32 + vc * 4 + 3];
    // W2 reg planes j=0..7 of k-group g2 (rows 4u..4u+3 of block slice)
    const size_t w2base = (size_t)g2 * 32 * 1024 + (size_t)q * 256 + u;
    const float4 w2c0 = w2T4[w2base + 0 * 1024];
    const float4 w2c1 = w2T4[w2base + 1 * 1024];
    const float4 w2c2 = w2T4[w2base + 2 * 1024];
    const float4 w2c3 = w2T4[w2base + 3 * 1024];
    const float4 w2c4 = w2T4[w2base + 4 * 1024];
    const float4 w2c5 = w2T4[w2base + 5 * 1024];
    const float4 w2c6 = w2T4[w2base + 6 * 1024];
    const float4 w2c7 = w2T4[w2base + 7 * 1024];
    // W2 LDS planes j=8..15 of each k-group (32 planes, 128 KB), loaded once
    for (int it = 0; it < 8; ++it) {
        int L   = it * 1024 + tid;
        int g2l = L >> 11;
        int jl  = (L >> 8) & 7;
        int ul  = L & 255;
        w2lds[g2l][jl][ul] =
            w2T4[(size_t)(g2l * 32 + 8 + jl) * 1024 + (size_t)q * 256 + ul];
    }

    const float b0r = (tid < W_) ? b0[tid] : 0.f;
    const float b1r = b1[vr];
    float4 b2c = make_float4(0.f, 0.f, 0.f, 0.f);
    if (tid < 256) b2c = reinterpret_cast<const float4*>(b2)[q * 256 + tid];
    float4 dx4 = make_float4(0.f, 0.f, 0.f, 0.f);
    __syncthreads();   // w2lds ready

    // ---------------- ODE: 99 intervals x 2 dopri5 substeps ------------------
    for (int i = 0; i < T_ - L_IN - 1; ++i) {
        float dt = tvals[L_IN + i + 1] - tvals[L_IN + i];
        hh = dt * 0.5f;   // N_SUB = 2
        if (tid < XC_) {
            float xa, xbv;
            if (tid < XC_ - 1) {
                xa  = cx[(b * T_ + L_IN + i) * (XC_ - 1) + tid];
                xbv = cx[(b * T_ + L_IN + i + 1) * (XC_ - 1) + tid];
            } else {
                xa  = tvals[L_IN + i];
                xbv = tvals[L_IN + i + 1];
            }
            dxs[tid] = (xbv - xa) / dt;
        }
        __syncthreads();
        if (tid < 256) {
            int c0 = (tid & 3) * 4;
            dx4 = make_float4(dxs[c0], dxs[c0 + 1], dxs[c0 + 2], dxs[c0 + 3]);
        }

        for (int sub = 0; sub < 2; ++sub) {
            if (tid < ZPB) zsq[tid] = z[q * ZPB + tid];
            __syncthreads();

            for (int s = 0; s < 6; ++s) {
                epoch++;
                // ---- V: v-partial = W0own @ zsq, wave-shuffle reduce --------
                {
                    const float* zp = &zsq[vc * 8];
                    float pv = w0r0.x * zp[0] + w0r0.y * zp[1]
                             + w0r0.z * zp[2] + w0r0.w * zp[3]
                             + w0r1.x * zp[4] + w0r1.y * zp[5]
                             + w0r1.z * zp[6] + w0r1.w * zp[7];
                    pv += __shfl_xor(pv, 1);
                    pv += __shfl_xor(pv, 2);
                    pv += __shfl_xor(pv, 4);
                    if ((ln & 7) == 0) {
                        vown[vr] = pv;
                        publish_u64(vr, pv);
                    }
                }
                __syncthreads();   // 1
                // ---- GATHER: 384 threads, one tagged u64 each ---------------
                if (tid < 384 && !dead) {
                    int pp = tid >> 7;
                    int e  = tid & 127;
                    int qq = pp + (pp >= q);
                    red[pp][e] = poll_u64(qq, e);
                }
                __syncthreads();   // 2
                // ---- A0 ----------------------------------------------------
                if (tid < W_) {
                    float gv = vown[tid] + red[0][tid] + red[1][tid]
                             + red[2][tid] + b0r;
                    a0s[tid] = softplus_f(gv);
                }
                __syncthreads();   // 3
                // ---- A1: W1 @ a0, wave-shuffle reduce -----------------------
                {
                    const float4* ap = reinterpret_cast<const float4*>(a0s) + vc * 4;
                    float4 a0v = ap[0], a1v = ap[1], a2v = ap[2], a3v = ap[3];
                    float pa = w1r0.x * a0v.x + w1r0.y * a0v.y
                             + w1r0.z * a0v.z + w1r0.w * a0v.w
                             + w1r1.x * a1v.x + w1r1.y * a1v.y
                             + w1r1.z * a1v.z + w1r1.w * a1v.w
                             + w1r2.x * a2v.x + w1r2.y * a2v.y
                             + w1r2.z * a2v.z + w1r2.w * a2v.w
                             + w1r3.x * a3v.x + w1r3.y * a3v.y
                             + w1r3.z * a3v.z + w1r3.w * a3v.w;
                    pa += __shfl_xor(pa, 1);
                    pa += __shfl_xor(pa, 2);
                    pa += __shfl_xor(pa, 4);
                    if ((ln & 7) == 0) a1s[vr] = softplus_f(pa + b1r);
                }
                __syncthreads();   // 4
                // ---- W2: 8 reg + 8 LDS + 16 streamed planes -----------------
                {
                    const int base = g2 * 32;
                    float4 acc = make_float4(0.f, 0.f, 0.f, 0.f);
                    #define W2MAC(c_, idx_) { float av_ = a1s[base + (idx_)]; \
                        acc.x += (c_).x * av_; acc.y += (c_).y * av_; \
                        acc.z += (c_).z * av_; acc.w += (c_).w * av_; }
                    W2MAC(w2c0, 0) W2MAC(w2c1, 1) W2MAC(w2c2, 2) W2MAC(w2c3, 3)
                    W2MAC(w2c4, 4) W2MAC(w2c5, 5) W2MAC(w2c6, 6) W2MAC(w2c7, 7)
                    #pragma unroll
                    for (int jl = 0; jl < 8; ++jl) {
                        float4 wvv = w2lds[g2][jl][u];
                        float av = a1s[base + 8 + jl];
                        acc.x += wvv.x * av; acc.y += wvv.y * av;
                        acc.z += wvv.z * av; acc.w += wvv.w * av;
                    }
                    const float4* wp = w2T4 + (size_t)(base + 16) * 1024
                                     + (size_t)q * 256 + u;
                    #pragma unroll 4
                    for (int js = 0; js < 16; ++js) {
                        float4 wvv = wp[(size_t)js * 1024];
                        float av = a1s[base + 16 + js];
                        acc.x += wvv.x * av; acc.y += wvv.y * av;
                        acc.z += wvv.z * av; acc.w += wvv.w * av;
                    }
                    #undef W2MAC
                    red4[g2][u] = acc;
                }
                __syncthreads();   // 5
                // ---- COMBINE: k-reduce, tanh, dx-dot, state update ----------
                if (tid < 256) {
                    float4 t0 = red4[0][tid], t1 = red4[1][tid];
                    float4 t2 = red4[2][tid], t3 = red4[3][tid];
                    float p = tanhf(t0.x + t1.x + t2.x + t3.x + b2c.x) * dx4.x
                            + tanhf(t0.y + t1.y + t2.y + t3.y + b2c.y) * dx4.y
                            + tanhf(t0.z + t1.z + t2.z + t3.z + b2c.z) * dx4.z
                            + tanhf(t0.w + t1.w + t2.w + t3.w + b2c.w) * dx4.w;
                    p += __shfl_xor(p, 1);
                    p += __shfl_xor(p, 2);
                    if ((tid & 3) == 0) {
                        int ii = tid >> 2;
                        float kv = p;
                        float zc = z[q * ZPB + ii];
                        if (s == 0) {
                            kbq[0][ii] = kv;
                            zsq[ii] = zc + hh * (0.2f * kv);
                        } else if (s == 1) {
                            kbq[1][ii] = kv;
                            zsq[ii] = zc + hh * (0.075f * kbq[0][ii] + 0.225f * kv);
                        } else if (s == 2) {
                            kbq[2][ii] = kv;
                            zsq[ii] = zc + hh * ((44.f / 45.f) * kbq[0][ii]
                                               - (56.f / 15.f) * kbq[1][ii]
                                               + (32.f / 9.f) * kv);
                        } else if (s == 3) {
                            kbq[3][ii] = kv;
                            zsq[ii] = zc + hh * ((19372.f / 6561.f) * kbq[0][ii]
                                               - (25360.f / 2187.f) * kbq[1][ii]
                                               + (64448.f / 6561.f) * kbq[2][ii]
                                               - (212.f / 729.f) * kv);
                        } else if (s == 4) {
                            kbq[4][ii] = kv;
                            zsq[ii] = zc + hh * ((9017.f / 3168.f) * kbq[0][ii]
                                               - (355.f / 33.f) * kbq[1][ii]
                                               + (46732.f / 5247.f) * kbq[2][ii]
                                               + (49.f / 176.f) * kbq[3][ii]
                                               - (5103.f / 18656.f) * kv);
                        } else {
                            z[q * ZPB + ii] = zc + hh * ((35.f / 384.f) * kbq[0][ii]
                                                       + (500.f / 1113.f) * kbq[2][ii]
                                                       + (125.f / 192.f) * kbq[3][ii]
                                                       - (2187.f / 6784.f) * kbq[4][ii]
                                                       + (11.f / 84.f) * kv);
                        }
                    }
                }
                __syncthreads();   // 6
            }   // stages
        }       // substeps

        // ---- z to block 0 for readout (one-way) ----
        epoch++;
        if (tid < ZPB) publish_u64(tid, z[q * ZPB + tid]);
        if (q == 0 && tid >= 64 && tid < 256 && !dead) {
            int pp = tid >> 6;       // 1..3
            int e  = tid & 63;
            z[pp * 64 + e] = poll_u64(pp, e);
        }
        __syncthreads();
        readout(i + 1);
    }
}

// ---------------------------------------------------------------------------
// Fallback (ws too small): monolithic kernel, original weight layouts.
// ---------------------------------------------------------------------------
__global__ __launch_bounds__(NT) void gru_cde_mono(
    const float* __restrict__ y_past, const float* __restrict__ tvals,
    const float* __restrict__ cx,
    const float* __restrict__ wih, const float* __restrict__ whh,
    const float* __restrict__ gru_b, const float* __restrict__ gru_bn,
    const float* __restrict__ w0, const float* __restrict__ b0,
    const float* __restrict__ w1, const float* __restrict__ b1,
    const float* __restrict__ w2, const float* __restrict__ b2,
    const float* __restrict__ ro_w, const float* __restrict__ ro_b,
    float* __restrict__ out)
{
    const int b   = blockIdx.x;
    const int tid = threadIdx.x;

    __shared__ __align__(16) float z[H_];
    __shared__ float zsv[H_];
    __shared__ float kbv[6][H_];
    __shared__ float a0v[W_];
    __shared__ float a1v[W_];
    __shared__ float redv[8][W_];
    __shared__ float gsum[GR_];
    __shared__ float gaux[H_];
    __shared__ float xb[S_ + XC_];
    __shared__ float dxsv[XC_];

    const float gb_t = (tid < GR_) ? gru_b[tid] : 0.f;
    const float bn_t = (tid < H_) ? gru_bn[tid] : 0.f;
    const float4 bb = reinterpret_cast<const float4*>(b2)[tid];

    if (tid < H_) z[tid] = 0.f;
    __syncthreads();

    for (int step = 0; step < L_IN; ++step) {
        if (tid < S_ + XC_) {
            float v;
            if (tid < S_)                v = y_past[(b * L_IN + step) * S_ + tid];
            else if (tid < S_ + XC_ - 1) v = cx[(b * T_ + step) * (XC_ - 1) + (tid - S_)];
            else                         v = tvals[step];
            xb[tid] = v;
        }
        __syncthreads();
        if (tid < GR_) {
            float ig = gb_t;
            #pragma unroll
            for (int k = 0; k < S_ + XC_; ++k) ig += wih[tid * (S_ + XC_) + k] * xb[k];
            float hg = 0.f;
            #pragma unroll 8
            for (int k = 0; k < H_; ++k) hg += whh[tid * H_ + k] * z[k];
            if (tid < 2 * H_) gsum[tid] = ig + hg;
            else { gsum[tid] = ig; gaux[tid - 2 * H_] = hg; }
        }
        __syncthreads();
        if (tid < H_) {
            float r = sigmoid_f(gsum[tid]);
            float u = sigmoid_f(gsum[tid + H_]);
            float n = tanhf(gsum[tid + 2 * H_] + r * (gaux[tid] + bn_t));
            z[tid] = n + u * (z[tid] - n);
        }
        __syncthreads();
    }

    auto readout = [&](int idx) {
        if (tid < 8 * 64) {
            int o  = tid >> 6;
            int kk = tid & 63;
            float4 wv = reinterpret_cast<const float4*>(ro_w)[o * 64 + kk];
            float4 zv = *reinterpret_cast<const float4*>(&z[kk * 4]);
            float p = wv.x * zv.x + wv.y * zv.y + wv.z * zv.z + wv.w * zv.w;
            p += __shfl_xor(p, 1);
            p += __shfl_xor(p, 2);
            p += __shfl_xor(p, 4);
            p += __shfl_xor(p, 8);
            p += __shfl_xor(p, 16);
            p += __shfl_xor(p, 32);
            if (kk == 0) out[(b * L_IN + idx) * O_ + o] = p + ro_b[o];
        }
    };

    readout(0);

    auto vf = [&](const float* zin, int s) {
        const int g = tid >> 7;
        const int r = tid & 127;
        {
            float acc = 0.f;
            const int k0 = g * 32;
            #pragma unroll 8
            for (int k = k0; k < k0 + 32; ++k) acc += w0[r * H_ + k] * zin[k];
            redv[g][r] = acc;
        }
        __syncthreads();
        if (tid < W_) {
            float sa = b0[tid];
            #pragma unroll
            for (int gg = 0; gg < 8; ++gg) sa += redv[gg][tid];
            a0v[tid] = softplus_f(sa);
        }
        __syncthreads();
        {
            float acc = 0.f;
            const int k0 = g * 16;
            #pragma unroll
            for (int k = k0; k < k0 + 16; ++k) acc += w1[r * W_ + k] * a0v[k];
            redv[g][r] = acc;
        }
        __syncthreads();
        if (tid < W_) {
            float sa = b1[tid];
            #pragma unroll
            for (int gg = 0; gg < 8; ++gg) sa += redv[gg][tid];
            a1v[tid] = softplus_f(sa);
        }
        __syncthreads();
        {
            float4 acc = make_float4(0.f, 0.f, 0.f, 0.f);
            const int jj = tid * 4;
            #pragma unroll 4
            for (int k = 0; k < W_; ++k) {
                float av = a1v[k];
                acc.x += w2[(jj + 0) * W_ + k] * av;
                acc.y += w2[(jj + 1) * W_ + k] * av;
                acc.z += w2[(jj + 2) * W_ + k] * av;
                acc.w += w2[(jj + 3) * W_ + k] * av;
            }
            const int c0 = jj & 15;
            float p = tanhf(acc.x + bb.x) * dxsv[c0]
                    + tanhf(acc.y + bb.y) * dxsv[c0 + 1]
                    + tanhf(acc.z + bb.z) * dxsv[c0 + 2]
                    + tanhf(acc.w + bb.w) * dxsv[c0 + 3];
            p += __shfl_xor(p, 1);
            p += __shfl_xor(p, 2);
            if ((tid & 3) == 0) kbv[s][tid >> 2] = p;
        }
        __syncthreads();
    };

    for (int i = 0; i < T_ - L_IN - 1; ++i) {
        float dt = tvals[L_IN + i + 1] - tvals[L_IN + i];
        if (tid < XC_) {
            float xa, xbv;
            if (tid < XC_ - 1) {
                xa  = cx[(b * T_ + L_IN + i) * (XC_ - 1) + tid];
                xbv = cx[(b * T_ + L_IN + i + 1) * (XC_ - 1) + tid];
            } else {
                xa  = tvals[L_IN + i];
                xbv = tvals[L_IN + i + 1];
            }
            dxsv[tid] = (xbv - xa) / dt;
        }
        const float hh = dt * 0.5f;
        __syncthreads();

        for (int sub = 0; sub < 2; ++sub) {
            vf(z, 0);
            if (tid < H_) zsv[tid] = z[tid] + hh * (0.2f * kbv[0][tid]);
            __syncthreads();
            vf(zsv, 1);
            if (tid < H_) zsv[tid] = z[tid] + hh * (0.075f * kbv[0][tid] + 0.225f * kbv[1][tid]);
            __syncthreads();
            vf(zsv, 2);
            if (tid < H_) zsv[tid] = z[tid] + hh * ((44.f / 45.f) * kbv[0][tid]
                                                - (56.f / 15.f) * kbv[1][tid]
                                                + (32.f / 9.f) * kbv[2][tid]);
            __syncthreads();
            vf(zsv, 3);
            if (tid < H_) zsv[tid] = z[tid] + hh * ((19372.f / 6561.f) * kbv[0][tid]
                                                - (25360.f / 2187.f) * kbv[1][tid]
                                                + (64448.f / 6561.f) * kbv[2][tid]
                                                - (212.f / 729.f) * kbv[3][tid]);
            __syncthreads();
            vf(zsv, 4);
            if (tid < H_) zsv[tid] = z[tid] + hh * ((9017.f / 3168.f) * kbv[0][tid]
                                                - (355.f / 33.f) * kbv[1][tid]
                                                + (46732.f / 5247.f) * kbv[2][tid]
                                                + (49.f / 176.f) * kbv[3][tid]
                                                - (5103.f / 18656.f) * kbv[4][tid]);
            __syncthreads();
            vf(zsv, 5);
            if (tid < H_) {
                z[tid] = z[tid] + hh * ((35.f / 384.f) * kbv[0][tid]
                                      + (500.f / 1113.f) * kbv[2][tid]
                                      + (125.f / 192.f) * kbv[3][tid]
                                      - (2187.f / 6784.f) * kbv[4][tid]
                                      + (11.f / 84.f) * kbv[5][tid]);
            }
            __syncthreads();
        }
        readout(i + 1);
    }
}

extern "C" void kernel_launch(void* const* d_in, const int* in_sizes, int n_in,
                              void* d_out, int out_size, void* d_ws, size_t ws_size,
                              hipStream_t stream) {
    const float* y_past = (const float*)d_in[0];
    const float* tvals  = (const float*)d_in[1];
    const float* cx     = (const float*)d_in[2];
    const float* wih    = (const float*)d_in[3];
    const float* whh    = (const float*)d_in[4];
    const float* gb     = (const float*)d_in[5];
    const float* gbn    = (const float*)d_in[6];
    const float* w0     = (const float*)d_in[7];
    const float* b0     = (const float*)d_in[8];
    const float* w1     = (const float*)d_in[9];
    const float* b1     = (const float*)d_in[10];
    const float* w2     = (const float*)d_in[11];
    const float* b2     = (const float*)d_in[12];
    const float* ro_w   = (const float*)d_in[13];
    const float* ro_b   = (const float*)d_in[14];
    float* out = (float*)d_out;

    if (ws_size >= WS_FLOATS * sizeof(float)) {
        float* ws = (float*)d_ws;
        auto launchT = [&](const float* in, float* o, int R, int K) {
            int n = R * K;
            transpose_kernel<<<(n + 255) / 256, 256, 0, stream>>>(in, o, R, K);
        };
        launchT(wih, ws + OFF_WIHT, GR_, S_ + XC_);
        launchT(whh, ws + OFF_WHHT, GR_, H_);
        launchT(w2,  ws + OFF_W2T,  HXC, W_);
        // zero the tagged-exchange buffer (tags must start below epoch 1)
        hipMemsetAsync((char*)d_ws + OFF_KX * sizeof(float), 0,
                       KX_U64 * sizeof(unsigned long long), stream);
        gru_cde_dist<<<B_ * NB, NT, 0, stream>>>(
            y_past, tvals, cx,
            ws + OFF_WIHT, ws + OFF_WHHT, gb, gbn,
            w0, b0, w1, b1, ws + OFF_W2T, b2,
            ro_w, ro_b,
            (unsigned long long*)(ws + OFF_KX), out);
    } else {
        gru_cde_mono<<<B_, NT, 0, stream>>>(
            y_past, tvals, cx,
            wih, whh, gb, gbn,
            w0, b0, w1, b1, w2, b2,
            ro_w, ro_b, out);
    }
}

// Round 12
// 8543.250 us; speedup vs baseline: 2.2384x; 1.1250x over previous
//
#include <hip/hip_runtime.h>
#include <math.h>

// Problem constants (match reference)
constexpr int B_   = 64;
constexpr int T_   = 200;
constexpr int L_IN = 100;
constexpr int S_   = 8;
constexpr int XC_  = 16;
constexpr int H_   = 256;
constexpr int W_   = 128;
constexpr int O_   = 8;
constexpr int GR_  = 3 * H_;      // 768
constexpr int HXC  = H_ * XC_;    // 4096

constexpr int NB   = 4;           // blocks per batch (team)
constexpr int ZPB  = 64;          // z-rows per block
constexpr int SLOT = 128;         // exchange payload slot (u64 elements)

#define NT 1024

// Workspace layout (floats) — kept identical to R8/R11 (unused slots harmless)
constexpr size_t OFF_WIHT = 0;                               // (unused now)
constexpr size_t OFF_WHHT = OFF_WIHT + 24ull * GR_;          // (unused now)
constexpr size_t OFF_W2T  = OFF_WHHT + (size_t)H_ * GR_;     // [128][4096] k-major
constexpr size_t OFF_KX   = OFF_W2T + (size_t)W_ * HXC;      // [64][2][4][128] u64
constexpr size_t KX_U64   = (size_t)B_ * 2 * NB * SLOT;      // 65536 u64
constexpr size_t WS_FLOATS = OFF_KX + KX_U64 * 2;            // ~3.48 MB

// Transpose: in is R x K row-major; out[k*R + j] = in[j*K + k]
__global__ void transpose_kernel(const float* __restrict__ in, float* __restrict__ out,
                                 int R, int K) {
    int o = blockIdx.x * blockDim.x + threadIdx.x;
    if (o < R * K) {
        int k = o / R;
        int j = o - k * R;
        out[o] = in[j * K + k];
    }
}

__device__ __forceinline__ float softplus_f(float x) {
    return fmaxf(x, 0.f) + log1pf(expf(-fabsf(x)));
}
__device__ __forceinline__ float sigmoid_f(float x) {
    return 1.f / (1.f + expf(-x));
}

// ---------------------------------------------------------------------------
// R12 = R8 frame (proven 9.6 ms, tagged-u64 single-RT exchange, LDS W2 tile)
// + two low-risk edits:
//  (1) GATHER+A0 fused into one phase: 128 threads run a CONCURRENT 3-way
//      poll (all peer loads issued per spin iteration) then softplus inline.
//      5 barriers/stage instead of 6; red[] LDS round-trip removed.
//  (2) Encoder matvec vectorized: original row-major wih/whh, per-thread
//      float4 streaming (64 wide loads vs 256 scalar) for the 3 active waves.
// NOTE: the compiler hard-caps this kernel at 64 VGPRs (R9/R11 evidence) —
// no register-residency schemes beyond ~30 persistent VGPRs are attempted.
// ---------------------------------------------------------------------------
__global__ __launch_bounds__(NT, 4) void gru_cde_dist(
    const float* __restrict__ y_past,   // [B][L_IN][S]
    const float* __restrict__ tvals,    // [T]
    const float* __restrict__ cx,       // [B][T][XC-1]
    const float* __restrict__ wih,      // [768][24] row-major (original)
    const float* __restrict__ whh,      // [768][256] row-major (original)
    const float* __restrict__ gru_b,    // [768]
    const float* __restrict__ gru_bn,   // [256]
    const float* __restrict__ w0,       // [128][256] row-major
    const float* __restrict__ b0,       // [128]
    const float* __restrict__ w1,       // [128][128] row-major
    const float* __restrict__ b1,       // [128]
    const float* __restrict__ w2T,      // [128][4096] k-major
    const float* __restrict__ b2,       // [4096]
    const float* __restrict__ ro_w,     // [8][256]
    const float* __restrict__ ro_b,     // [8]
    unsigned long long* __restrict__ kx, // [64][2][4][128] tagged payload
    float* __restrict__ out)            // [B][100][8]
{
    const int b   = blockIdx.x & (B_ - 1);   // batch
    const int q   = blockIdx.x >> 6;         // quarter 0..3
    const int tid = threadIdx.x;

    __shared__ __align__(16) float z[H_];
    __shared__ __align__(16) float zsq[ZPB];
    __shared__ float kbq[5][ZPB];
    __shared__ __align__(16) float a0s[W_];
    __shared__ __align__(16) float a1s[W_];
    __shared__ float vown[W_];
    __shared__ __align__(16) float4 red4[4][256];
    __shared__ float gsum[192];
    __shared__ float gaux[ZPB];
    __shared__ __align__(16) float xb[S_ + XC_];
    __shared__ float dxs[XC_];
    __shared__ __align__(16) float4 w2lds[4][8][256];   // 128 KB: 32 W2 k-planes

    int  epoch = 0;
    bool dead  = false;
    float hh   = 0.f;

    auto slotbase = [&](int qq) -> size_t {
        return (((size_t)b * 2 + (epoch & 1)) * NB + qq) * SLOT;
    };
    auto publish_u64 = [&](int elem, float v) {
        unsigned long long pk = ((unsigned long long)(unsigned)epoch << 32)
                              | (unsigned long long)__float_as_uint(v);
        __hip_atomic_store(&kx[slotbase(q) + elem], pk,
                           __ATOMIC_RELAXED, __HIP_MEMORY_SCOPE_AGENT);
    };
    auto poll_u64 = [&](int qq, int elem) -> float {
        unsigned long long pk = 0;
        int guard = 0;
        for (;;) {
            pk = __hip_atomic_load(&kx[slotbase(qq) + elem],
                                   __ATOMIC_RELAXED, __HIP_MEMORY_SCOPE_AGENT);
            if ((unsigned)(pk >> 32) >= (unsigned)epoch) break;
            if (++guard > (1 << 20)) { dead = true; break; }
        }
        return __uint_as_float((unsigned)pk);
    };

    // ---------------- Encoder: 100 GRU steps, 2 syncs/step -------------------
    const int   seg = tid >> 6;          // 0=reset,1=update,2=new (tid<192)
    const int   l63 = tid & 63;
    const int   grow = seg * H_ + q * ZPB + l63;
    const float gbr = (tid < 192) ? gru_b[grow] : 0.f;
    const float bnr = (tid < ZPB) ? gru_bn[q * ZPB + tid] : 0.f;

    if (tid < H_) z[tid] = 0.f;
    if (tid < S_ + XC_) {    // xb for step 0
        float v;
        if (tid < S_)                v = y_past[(b * L_IN) * S_ + tid];
        else if (tid < S_ + XC_ - 1) v = cx[(b * T_) * (XC_ - 1) + (tid - S_)];
        else                         v = tvals[0];
        xb[tid] = v;
    }
    __syncthreads();

    for (int step = 0; step < L_IN; ++step) {
        if (tid < 192) {    // phase A: gate pre-activations (float4-streamed)
            const float4* xr = reinterpret_cast<const float4*>(xb);
            const float4* wr = reinterpret_cast<const float4*>(wih + grow * 24);
            float ig = gbr;
            #pragma unroll
            for (int c = 0; c < 6; ++c) {
                float4 wv = wr[c], xv = xr[c];
                ig += wv.x * xv.x + wv.y * xv.y + wv.z * xv.z + wv.w * xv.w;
            }
            const float4* hr = reinterpret_cast<const float4*>(whh + grow * 256);
            const float4* z4 = reinterpret_cast<const float4*>(z);
            float hg = 0.f, hg2 = 0.f;
            #pragma unroll 8
            for (int c = 0; c < 64; c += 2) {
                float4 wa = hr[c],     za = z4[c];
                float4 wb = hr[c + 1], zb = z4[c + 1];
                hg  += wa.x * za.x + wa.y * za.y + wa.z * za.z + wa.w * za.w;
                hg2 += wb.x * zb.x + wb.y * zb.y + wb.z * zb.z + wb.w * zb.w;
            }
            hg += hg2;
            if (seg < 2) gsum[tid] = ig + hg;
            else { gsum[tid] = ig; gaux[l63] = hg; }
        }
        __syncthreads();
        epoch++;
        // phase B: update+publish / gather / preload xb
        if (tid < ZPB) {
            float rr = sigmoid_f(gsum[tid]);
            float uu = sigmoid_f(gsum[64 + tid]);
            float nn = tanhf(gsum[128 + tid] + rr * (gaux[tid] + bnr));
            float zo = z[q * ZPB + tid];
            float znew = nn + uu * (zo - nn);
            z[q * ZPB + tid] = znew;
            publish_u64(tid, znew);
        } else if (tid < 256) {
            if (!dead) {
                int pp = tid >> 6;               // 1..3
                int qq = (q + pp) & 3;
                int e  = tid & 63;
                float v = poll_u64(qq, e);
                z[qq * 64 + e] = v;
            }
        } else if (tid < 256 + S_ + XC_ && step + 1 < L_IN) {
            int c = tid - 256;
            float v;
            if (c < S_)                v = y_past[(b * L_IN + step + 1) * S_ + c];
            else if (c < S_ + XC_ - 1) v = cx[(b * T_ + step + 1) * (XC_ - 1) + (c - S_)];
            else                       v = tvals[step + 1];
            xb[c] = v;
        }
        __syncthreads();
    }

    // readout (block q==0 only; its z is full after encoder gathers)
    auto readout = [&](int idx) {
        if (q == 0 && tid < 8 * 64) {
            int o  = tid >> 6;
            int kk = tid & 63;
            float4 wv = reinterpret_cast<const float4*>(ro_w)[o * 64 + kk];
            float4 zv = *reinterpret_cast<const float4*>(&z[kk * 4]);
            float p = wv.x * zv.x + wv.y * zv.y + wv.z * zv.z + wv.w * zv.w;
            p += __shfl_xor(p, 1);
            p += __shfl_xor(p, 2);
            p += __shfl_xor(p, 4);
            p += __shfl_xor(p, 8);
            p += __shfl_xor(p, 16);
            p += __shfl_xor(p, 32);
            if (kk == 0) out[(b * L_IN + idx) * O_ + o] = p + ro_b[o];
        }
    };

    readout(0);

    // ---------------- ODE weight residency ----------------------------------
    const int wv_ = tid >> 6;            // wave 0..15
    const int ln  = tid & 63;            // lane
    const int vr  = wv_ * 8 + (ln >> 3); // matvec row 0..127
    const int vc  = ln & 7;              // k-chunk 0..7
    const int g2  = tid >> 8;            // W2 k-group 0..3
    const int u   = tid & 255;           // W2 row-quad 0..255

    const float4* __restrict__ w04  = reinterpret_cast<const float4*>(w0);
    const float4* __restrict__ w14  = reinterpret_cast<const float4*>(w1);
    const float4* __restrict__ w2T4 = reinterpret_cast<const float4*>(w2T);

    // W0 row vr, cols q*64 + vc*8 .. +7  (8 floats)
    const float4 w0r0 = w04[vr * 64 + q * 16 + vc * 2];
    const float4 w0r1 = w04[vr * 64 + q * 16 + vc * 2 + 1];
    // W1 row vr, cols vc*16 .. +15  (16 floats)
    const float4 w1r0 = w14[vr * 32 + vc * 4 + 0];
    const float4 w1r1 = w14[vr * 32 + vc * 4 + 1];
    const float4 w1r2 = w14[vr * 32 + vc * 4 + 2];
    const float4 w1r3 = w14[vr * 32 + vc * 4 + 3];
    // W2 reg planes j=0..7 of k-group g2 (rows 4u..4u+3 of block slice)
    const size_t w2base = (size_t)g2 * 32 * 1024 + (size_t)q * 256 + u;
    const float4 w2c0 = w2T4[w2base + 0 * 1024];
    const float4 w2c1 = w2T4[w2base + 1 * 1024];
    const float4 w2c2 = w2T4[w2base + 2 * 1024];
    const float4 w2c3 = w2T4[w2base + 3 * 1024];
    const float4 w2c4 = w2T4[w2base + 4 * 1024];
    const float4 w2c5 = w2T4[w2base + 5 * 1024];
    const float4 w2c6 = w2T4[w2base + 6 * 1024];
    const float4 w2c7 = w2T4[w2base + 7 * 1024];
    // W2 LDS planes j=8..15 of each k-group (32 planes, 128 KB), loaded once
    for (int it = 0; it < 8; ++it) {
        int L   = it * 1024 + tid;
        int g2l = L >> 11;
        int jl  = (L >> 8) & 7;
        int ul  = L & 255;
        w2lds[g2l][jl][ul] =
            w2T4[(size_t)(g2l * 32 + 8 + jl) * 1024 + (size_t)q * 256 + ul];
    }

    const float b0r = (tid < W_) ? b0[tid] : 0.f;
    const float b1r = b1[vr];
    float4 b2c = make_float4(0.f, 0.f, 0.f, 0.f);
    if (tid < 256) b2c = reinterpret_cast<const float4*>(b2)[q * 256 + tid];
    float4 dx4 = make_float4(0.f, 0.f, 0.f, 0.f);
    __syncthreads();   // w2lds ready

    // ---------------- ODE: 99 intervals x 2 dopri5 substeps ------------------
    for (int i = 0; i < T_ - L_IN - 1; ++i) {
        float dt = tvals[L_IN + i + 1] - tvals[L_IN + i];
        hh = dt * 0.5f;   // N_SUB = 2
        if (tid < XC_) {
            float xa, xbv;
            if (tid < XC_ - 1) {
                xa  = cx[(b * T_ + L_IN + i) * (XC_ - 1) + tid];
                xbv = cx[(b * T_ + L_IN + i + 1) * (XC_ - 1) + tid];
            } else {
                xa  = tvals[L_IN + i];
                xbv = tvals[L_IN + i + 1];
            }
            dxs[tid] = (xbv - xa) / dt;
        }
        __syncthreads();
        if (tid < 256) {
            int c0 = (tid & 3) * 4;
            dx4 = make_float4(dxs[c0], dxs[c0 + 1], dxs[c0 + 2], dxs[c0 + 3]);
        }

        for (int sub = 0; sub < 2; ++sub) {
            if (tid < ZPB) zsq[tid] = z[q * ZPB + tid];
            __syncthreads();

            for (int s = 0; s < 6; ++s) {
                epoch++;
                // ---- V: v-partial = W0own @ zsq, wave-shuffle reduce --------
                {
                    const float* zp = &zsq[vc * 8];
                    float pv = w0r0.x * zp[0] + w0r0.y * zp[1]
                             + w0r0.z * zp[2] + w0r0.w * zp[3]
                             + w0r1.x * zp[4] + w0r1.y * zp[5]
                             + w0r1.z * zp[6] + w0r1.w * zp[7];
                    pv += __shfl_xor(pv, 1);
                    pv += __shfl_xor(pv, 2);
                    pv += __shfl_xor(pv, 4);
                    if ((ln & 7) == 0) {
                        vown[vr] = pv;
                        publish_u64(vr, pv);
                    }
                }
                __syncthreads();   // 1
                // ---- GATHER+A0 fused: concurrent 3-way poll + softplus ------
                if (tid < W_) {
                    float gv = vown[tid] + b0r;
                    if (!dead) {
                        const size_t s1 = slotbase((q + 1) & 3) + tid;
                        const size_t s2 = slotbase((q + 2) & 3) + tid;
                        const size_t s3 = slotbase((q + 3) & 3) + tid;
                        unsigned long long p1 = 0, p2 = 0, p3 = 0;
                        bool d1 = false, d2 = false, d3 = false;
                        int guard = 0;
                        do {
                            if (!d1) {
                                p1 = __hip_atomic_load(&kx[s1], __ATOMIC_RELAXED,
                                                       __HIP_MEMORY_SCOPE_AGENT);
                                d1 = (unsigned)(p1 >> 32) >= (unsigned)epoch;
                            }
                            if (!d2) {
                                p2 = __hip_atomic_load(&kx[s2], __ATOMIC_RELAXED,
                                                       __HIP_MEMORY_SCOPE_AGENT);
                                d2 = (unsigned)(p2 >> 32) >= (unsigned)epoch;
                            }
                            if (!d3) {
                                p3 = __hip_atomic_load(&kx[s3], __ATOMIC_RELAXED,
                                                       __HIP_MEMORY_SCOPE_AGENT);
                                d3 = (unsigned)(p3 >> 32) >= (unsigned)epoch;
                            }
                            if (++guard > (1 << 20)) { dead = true; break; }
                        } while (!(d1 && d2 && d3));
                        gv += __uint_as_float((unsigned)p1)
                            + __uint_as_float((unsigned)p2)
                            + __uint_as_float((unsigned)p3);
                    }
                    a0s[tid] = softplus_f(gv);
                }
                __syncthreads();   // 2
                // ---- A1: W1 @ a0, wave-shuffle reduce -----------------------
                {
                    const float4* ap = reinterpret_cast<const float4*>(a0s) + vc * 4;
                    float4 a0v = ap[0], a1v = ap[1], a2v = ap[2], a3v = ap[3];
                    float pa = w1r0.x * a0v.x + w1r0.y * a0v.y
                             + w1r0.z * a0v.z + w1r0.w * a0v.w
                             + w1r1.x * a1v.x + w1r1.y * a1v.y
                             + w1r1.z * a1v.z + w1r1.w * a1v.w
                             + w1r2.x * a2v.x + w1r2.y * a2v.y
                             + w1r2.z * a2v.z + w1r2.w * a2v.w
                             + w1r3.x * a3v.x + w1r3.y * a3v.y
                             + w1r3.z * a3v.z + w1r3.w * a3v.w;
                    pa += __shfl_xor(pa, 1);
                    pa += __shfl_xor(pa, 2);
                    pa += __shfl_xor(pa, 4);
                    if ((ln & 7) == 0) a1s[vr] = softplus_f(pa + b1r);
                }
                __syncthreads();   // 3
                // ---- W2: 8 reg + 8 LDS + 16 streamed planes -----------------
                {
                    const int base = g2 * 32;
                    float4 acc = make_float4(0.f, 0.f, 0.f, 0.f);
                    #define W2MAC(c_, idx_) { float av_ = a1s[base + (idx_)]; \
                        acc.x += (c_).x * av_; acc.y += (c_).y * av_; \
                        acc.z += (c_).z * av_; acc.w += (c_).w * av_; }
                    W2MAC(w2c0, 0) W2MAC(w2c1, 1) W2MAC(w2c2, 2) W2MAC(w2c3, 3)
                    W2MAC(w2c4, 4) W2MAC(w2c5, 5) W2MAC(w2c6, 6) W2MAC(w2c7, 7)
                    #pragma unroll
                    for (int jl = 0; jl < 8; ++jl) {
                        float4 wvv = w2lds[g2][jl][u];
                        float av = a1s[base + 8 + jl];
                        acc.x += wvv.x * av; acc.y += wvv.y * av;
                        acc.z += wvv.z * av; acc.w += wvv.w * av;
                    }
                    const float4* wp = w2T4 + (size_t)(base + 16) * 1024
                                     + (size_t)q * 256 + u;
                    #pragma unroll 4
                    for (int js = 0; js < 16; ++js) {
                        float4 wvv = wp[(size_t)js * 1024];
                        float av = a1s[base + 16 + js];
                        acc.x += wvv.x * av; acc.y += wvv.y * av;
                        acc.z += wvv.z * av; acc.w += wvv.w * av;
                    }
                    #undef W2MAC
                    red4[g2][u] = acc;
                }
                __syncthreads();   // 4
                // ---- COMBINE: k-reduce, tanh, dx-dot, state update ----------
                if (tid < 256) {
                    float4 t0 = red4[0][tid], t1 = red4[1][tid];
                    float4 t2 = red4[2][tid], t3 = red4[3][tid];
                    float p = tanhf(t0.x + t1.x + t2.x + t3.x + b2c.x) * dx4.x
                            + tanhf(t0.y + t1.y + t2.y + t3.y + b2c.y) * dx4.y
                            + tanhf(t0.z + t1.z + t2.z + t3.z + b2c.z) * dx4.z
                            + tanhf(t0.w + t1.w + t2.w + t3.w + b2c.w) * dx4.w;
                    p += __shfl_xor(p, 1);
                    p += __shfl_xor(p, 2);
                    if ((tid & 3) == 0) {
                        int ii = tid >> 2;
                        float kv = p;
                        float zc = z[q * ZPB + ii];
                        if (s == 0) {
                            kbq[0][ii] = kv;
                            zsq[ii] = zc + hh * (0.2f * kv);
                        } else if (s == 1) {
                            kbq[1][ii] = kv;
                            zsq[ii] = zc + hh * (0.075f * kbq[0][ii] + 0.225f * kv);
                        } else if (s == 2) {
                            kbq[2][ii] = kv;
                            zsq[ii] = zc + hh * ((44.f / 45.f) * kbq[0][ii]
                                               - (56.f / 15.f) * kbq[1][ii]
                                               + (32.f / 9.f) * kv);
                        } else if (s == 3) {
                            kbq[3][ii] = kv;
                            zsq[ii] = zc + hh * ((19372.f / 6561.f) * kbq[0][ii]
                                               - (25360.f / 2187.f) * kbq[1][ii]
                                               + (64448.f / 6561.f) * kbq[2][ii]
                                               - (212.f / 729.f) * kv);
                        } else if (s == 4) {
                            kbq[4][ii] = kv;
                            zsq[ii] = zc + hh * ((9017.f / 3168.f) * kbq[0][ii]
                                               - (355.f / 33.f) * kbq[1][ii]
                                               + (46732.f / 5247.f) * kbq[2][ii]
                                               + (49.f / 176.f) * kbq[3][ii]
                                               - (5103.f / 18656.f) * kv);
                        } else {
                            z[q * ZPB + ii] = zc + hh * ((35.f / 384.f) * kbq[0][ii]
                                                       + (500.f / 1113.f) * kbq[2][ii]
                                                       + (125.f / 192.f) * kbq[3][ii]
                                                       - (2187.f / 6784.f) * kbq[4][ii]
                                                       + (11.f / 84.f) * kv);
                        }
                    }
                }
                __syncthreads();   // 5
            }   // stages
        }       // substeps

        // ---- z to block 0 for readout (one-way) ----
        epoch++;
        if (tid < ZPB) publish_u64(tid, z[q * ZPB + tid]);
        if (q == 0 && tid >= 64 && tid < 256 && !dead) {
            int pp = tid >> 6;       // 1..3
            int e  = tid & 63;
            z[pp * 64 + e] = poll_u64(pp, e);
        }
        __syncthreads();
        readout(i + 1);
    }
}

// ---------------------------------------------------------------------------
// Fallback (ws too small): monolithic kernel, original weight layouts.
// ---------------------------------------------------------------------------
__global__ __launch_bounds__(NT) void gru_cde_mono(
    const float* __restrict__ y_past, const float* __restrict__ tvals,
    const float* __restrict__ cx,
    const float* __restrict__ wih, const float* __restrict__ whh,
    const float* __restrict__ gru_b, const float* __restrict__ gru_bn,
    const float* __restrict__ w0, const float* __restrict__ b0,
    const float* __restrict__ w1, const float* __restrict__ b1,
    const float* __restrict__ w2, const float* __restrict__ b2,
    const float* __restrict__ ro_w, const float* __restrict__ ro_b,
    float* __restrict__ out)
{
    const int b   = blockIdx.x;
    const int tid = threadIdx.x;

    __shared__ __align__(16) float z[H_];
    __shared__ float zsv[H_];
    __shared__ float kbv[6][H_];
    __shared__ float a0v[W_];
    __shared__ float a1v[W_];
    __shared__ float redv[8][W_];
    __shared__ float gsum[GR_];
    __shared__ float gaux[H_];
    __shared__ float xb[S_ + XC_];
    __shared__ float dxsv[XC_];

    const float gb_t = (tid < GR_) ? gru_b[tid] : 0.f;
    const float bn_t = (tid < H_) ? gru_bn[tid] : 0.f;
    const float4 bb = reinterpret_cast<const float4*>(b2)[tid];

    if (tid < H_) z[tid] = 0.f;
    __syncthreads();

    for (int step = 0; step < L_IN; ++step) {
        if (tid < S_ + XC_) {
            float v;
            if (tid < S_)                v = y_past[(b * L_IN + step) * S_ + tid];
            else if (tid < S_ + XC_ - 1) v = cx[(b * T_ + step) * (XC_ - 1) + (tid - S_)];
            else                         v = tvals[step];
            xb[tid] = v;
        }
        __syncthreads();
        if (tid < GR_) {
            float ig = gb_t;
            #pragma unroll
            for (int k = 0; k < S_ + XC_; ++k) ig += wih[tid * (S_ + XC_) + k] * xb[k];
            float hg = 0.f;
            #pragma unroll 8
            for (int k = 0; k < H_; ++k) hg += whh[tid * H_ + k] * z[k];
            if (tid < 2 * H_) gsum[tid] = ig + hg;
            else { gsum[tid] = ig; gaux[tid - 2 * H_] = hg; }
        }
        __syncthreads();
        if (tid < H_) {
            float r = sigmoid_f(gsum[tid]);
            float u = sigmoid_f(gsum[tid + H_]);
            float n = tanhf(gsum[tid + 2 * H_] + r * (gaux[tid] + bn_t));
            z[tid] = n + u * (z[tid] - n);
        }
        __syncthreads();
    }

    auto readout = [&](int idx) {
        if (tid < 8 * 64) {
            int o  = tid >> 6;
            int kk = tid & 63;
            float4 wv = reinterpret_cast<const float4*>(ro_w)[o * 64 + kk];
            float4 zv = *reinterpret_cast<const float4*>(&z[kk * 4]);
            float p = wv.x * zv.x + wv.y * zv.y + wv.z * zv.z + wv.w * zv.w;
            p += __shfl_xor(p, 1);
            p += __shfl_xor(p, 2);
            p += __shfl_xor(p, 4);
            p += __shfl_xor(p, 8);
            p += __shfl_xor(p, 16);
            p += __shfl_xor(p, 32);
            if (kk == 0) out[(b * L_IN + idx) * O_ + o] = p + ro_b[o];
        }
    };

    readout(0);

    auto vf = [&](const float* zin, int s) {
        const int g = tid >> 7;
        const int r = tid & 127;
        {
            float acc = 0.f;
            const int k0 = g * 32;
            #pragma unroll 8
            for (int k = k0; k < k0 + 32; ++k) acc += w0[r * H_ + k] * zin[k];
            redv[g][r] = acc;
        }
        __syncthreads();
        if (tid < W_) {
            float sa = b0[tid];
            #pragma unroll
            for (int gg = 0; gg < 8; ++gg) sa += redv[gg][tid];
            a0v[tid] = softplus_f(sa);
        }
        __syncthreads();
        {
            float acc = 0.f;
            const int k0 = g * 16;
            #pragma unroll
            for (int k = k0; k < k0 + 16; ++k) acc += w1[r * W_ + k] * a0v[k];
            redv[g][r] = acc;
        }
        __syncthreads();
        if (tid < W_) {
            float sa = b1[tid];
            #pragma unroll
            for (int gg = 0; gg < 8; ++gg) sa += redv[gg][tid];
            a1v[tid] = softplus_f(sa);
        }
        __syncthreads();
        {
            float4 acc = make_float4(0.f, 0.f, 0.f, 0.f);
            const int jj = tid * 4;
            #pragma unroll 4
            for (int k = 0; k < W_; ++k) {
                float av = a1v[k];
                acc.x += w2[(jj + 0) * W_ + k] * av;
                acc.y += w2[(jj + 1) * W_ + k] * av;
                acc.z += w2[(jj + 2) * W_ + k] * av;
                acc.w += w2[(jj + 3) * W_ + k] * av;
            }
            const int c0 = jj & 15;
            float p = tanhf(acc.x + bb.x) * dxsv[c0]
                    + tanhf(acc.y + bb.y) * dxsv[c0 + 1]
                    + tanhf(acc.z + bb.z) * dxsv[c0 + 2]
                    + tanhf(acc.w + bb.w) * dxsv[c0 + 3];
            p += __shfl_xor(p, 1);
            p += __shfl_xor(p, 2);
            if ((tid & 3) == 0) kbv[s][tid >> 2] = p;
        }
        __syncthreads();
    };

    for (int i = 0; i < T_ - L_IN - 1; ++i) {
        float dt = tvals[L_IN + i + 1] - tvals[L_IN + i];
        if (tid < XC_) {
            float xa, xbv;
            if (tid < XC_ - 1) {
                xa  = cx[(b * T_ + L_IN + i) * (XC_ - 1) + tid];
                xbv = cx[(b * T_ + L_IN + i + 1) * (XC_ - 1) + tid];
            } else {
                xa  = tvals[L_IN + i];
                xbv = tvals[L_IN + i + 1];
            }
            dxsv[tid] = (xbv - xa) / dt;
        }
        const float hh = dt * 0.5f;
        __syncthreads();

        for (int sub = 0; sub < 2; ++sub) {
            vf(z, 0);
            if (tid < H_) zsv[tid] = z[tid] + hh * (0.2f * kbv[0][tid]);
            __syncthreads();
            vf(zsv, 1);
            if (tid < H_) zsv[tid] = z[tid] + hh * (0.075f * kbv[0][tid] + 0.225f * kbv[1][tid]);
            __syncthreads();
            vf(zsv, 2);
            if (tid < H_) zsv[tid] = z[tid] + hh * ((44.f / 45.f) * kbv[0][tid]
                                                - (56.f / 15.f) * kbv[1][tid]
                                                + (32.f / 9.f) * kbv[2][tid]);
            __syncthreads();
            vf(zsv, 3);
            if (tid < H_) zsv[tid] = z[tid] + hh * ((19372.f / 6561.f) * kbv[0][tid]
                                                - (25360.f / 2187.f) * kbv[1][tid]
                                                + (64448.f / 6561.f) * kbv[2][tid]
                                                - (212.f / 729.f) * kbv[3][tid]);
            __syncthreads();
            vf(zsv, 4);
            if (tid < H_) zsv[tid] = z[tid] + hh * ((9017.f / 3168.f) * kbv[0][tid]
                                                - (355.f / 33.f) * kbv[1][tid]
                                                + (46732.f / 5247.f) * kbv[2][tid]
                                                + (49.f / 176.f) * kbv[3][tid]
                                                - (5103.f / 18656.f) * kbv[4][tid]);
            __syncthreads();
            vf(zsv, 5);
            if (tid < H_) {
                z[tid] = z[tid] + hh * ((35.f / 384.f) * kbv[0][tid]
                                      + (500.f / 1113.f) * kbv[2][tid]
                                      + (125.f / 192.f) * kbv[3][tid]
                                      - (2187.f / 6784.f) * kbv[4][tid]
                                      + (11.f / 84.f) * kbv[5][tid]);
            }
            __syncthreads();
        }
        readout(i + 1);
    }
}

extern "C" void kernel_launch(void* const* d_in, const int* in_sizes, int n_in,
                              void* d_out, int out_size, void* d_ws, size_t ws_size,
                              hipStream_t stream) {
    const float* y_past = (const float*)d_in[0];
    const float* tvals  = (const float*)d_in[1];
    const float* cx     = (const float*)d_in[2];
    const float* wih    = (const float*)d_in[3];
    const float* whh    = (const float*)d_in[4];
    const float* gb     = (const float*)d_in[5];
    const float* gbn    = (const float*)d_in[6];
    const float* w0     = (const float*)d_in[7];
    const float* b0     = (const float*)d_in[8];
    const float* w1     = (const float*)d_in[9];
    const float* b1     = (const float*)d_in[10];
    const float* w2     = (const float*)d_in[11];
    const float* b2     = (const float*)d_in[12];
    const float* ro_w   = (const float*)d_in[13];
    const float* ro_b   = (const float*)d_in[14];
    float* out = (float*)d_out;

    if (ws_size >= WS_FLOATS * sizeof(float)) {
        float* ws = (float*)d_ws;
        {   // w2 -> k-major transpose (only transpose still needed)
            int n = HXC * W_;
            transpose_kernel<<<(n + 255) / 256, 256, 0, stream>>>(
                w2, ws + OFF_W2T, HXC, W_);
        }
        // zero the tagged-exchange buffer (tags must start below epoch 1)
        hipMemsetAsync((char*)d_ws + OFF_KX * sizeof(float), 0,
                       KX_U64 * sizeof(unsigned long long), stream);
        gru_cde_dist<<<B_ * NB, NT, 0, stream>>>(
            y_past, tvals, cx,
            wih, whh, gb, gbn,
            w0, b0, w1, b1, ws + OFF_W2T, b2,
            ro_w, ro_b,
            (unsigned long long*)(ws + OFF_KX), out);
    } else {
        gru_cde_mono<<<B_, NT, 0, stream>>>(
            y_past, tvals, cx,
            wih, whh, gb, gbn,
            w0, b0, w1, b1, w2, b2,
            ro_w, ro_b, out);
    }
}